// Round 7
// baseline (341.938 us; speedup 1.0000x reference)
//
#include <hip/hip_runtime.h>

typedef unsigned short ushort;
typedef __bf16 bf16x8 __attribute__((ext_vector_type(8)));
typedef float f32x4 __attribute__((ext_vector_type(4)));

#define F_IN 256
#define CCH  128
#define BSH  7
#define BNODES 128
#define NBUCK 1024
#define CHUNK 2048

#define LDA 40    // ushort stride of staged A/B rows (BK=32 + 8 pad)
#define LDH 136   // ushort stride of h-tile rows

// ---------------- helpers ----------------
__device__ __forceinline__ ushort f2bf(float f) {
    union { float f; unsigned i; } u; u.f = f;
    unsigned r = u.i + 0x7fffu + ((u.i >> 16) & 1u);   // RNE
    return (ushort)(r >> 16);
}
__device__ __forceinline__ float2 bf2f2(unsigned u) {
    union { unsigned i; float f; } lo, hi;
    lo.i = u << 16;
    hi.i = u & 0xffff0000u;
    return make_float2(lo.f, hi.f);
}

// ---------------- K1: per-chunk histogram (dual layout) + weight cvt ----------------
__global__ __launch_bounds__(256)
void hist_cvt(const int* __restrict__ dst, int* __restrict__ histC, int* __restrict__ histT,
              int E, int nchunks, int ncp,
              const float* __restrict__ W1, const float* __restrict__ W2,
              ushort* __restrict__ w1b, ushort* __restrict__ w2b)
{
    const int blk = blockIdx.x, t = threadIdx.x;
    if (blk >= nchunks) {
        int i = (blk - nchunks) * 256 + t;
        if (i < CCH * F_IN) w1b[i] = f2bf(W1[i]);
        else {
            int j = i - CCH * F_IN;
            if (j < CCH * CCH) w2b[j] = f2bf(W2[j]);
        }
        return;
    }
    __shared__ int h[NBUCK];
    for (int i = t; i < NBUCK; i += 256) h[i] = 0;
    __syncthreads();
    int cb = blk * CHUNK, ce = min(cb + CHUNK, E);
    for (int e = cb + t; e < ce; e += 256)
        atomicAdd(&h[dst[e] >> BSH], 1);
    __syncthreads();
    for (int i = t; i < NBUCK; i += 256) {
        int v = h[i];
        histC[blk * NBUCK + i] = v;     // chunk-major (partition)
        histT[i * ncp + blk]   = v;     // bucket-major (scan)
    }
}

// ---------------- K2: per-bucket cross-chunk prefix (one wave per bucket) ----------------
__global__ __launch_bounds__(256)
void scan_buckets(const int* __restrict__ histT, int* __restrict__ prefT,
                  int* __restrict__ btot, int nchunks, int ncp)
{
    const int b = blockIdx.x * 4 + (threadIdx.x >> 6);
    const int lane = threadIdx.x & 63;
    int carry = 0;
    for (int c = 0; c < nchunks; c += 64) {
        int idx = c + lane;
        int v = (idx < nchunks) ? histT[b * ncp + idx] : 0;
        int inc = v;
#pragma unroll
        for (int off = 1; off < 64; off <<= 1) {
            int x = __shfl_up(inc, off, 64);
            if (lane >= off) inc += x;
        }
        if (idx < nchunks) prefT[b * ncp + idx] = carry + inc - v;
        carry += __shfl(inc, 63, 64);
    }
    if (lane == 0) btot[b] = carry;
}

// ---------------- K3: partition (deterministic slots, no global atomics) ----------------
__global__ __launch_bounds__(256)
void partition_kernel(const int* __restrict__ src, const int* __restrict__ dst,
                      const int* __restrict__ histC, const int* __restrict__ prefT,
                      const int* __restrict__ btot, int* __restrict__ gbase,
                      unsigned* __restrict__ pairs, int E, int ncp)
{
    __shared__ int lbase[NBUCK];
    __shared__ int lcur[NBUCK];
    __shared__ int rb2[NBUCK];
    __shared__ int base_s[NBUCK];
    __shared__ int ssum[256];
    __shared__ unsigned sp[CHUNK];   // 8 KB
    __shared__ ushort  sb[CHUNK];    // 4 KB
    const int t = threadIdx.x, blk = blockIdx.x;

    // scan this chunk's hist -> lbase/lcur
    int4 cv = *(const int4*)&histC[blk * NBUCK + 4 * t];
    int tsum = cv.x + cv.y + cv.z + cv.w;
    ssum[t] = tsum;
    __syncthreads();
    for (int off = 1; off < 256; off <<= 1) {
        int x = (t >= off) ? ssum[t - off] : 0;
        __syncthreads();
        ssum[t] += x;
        __syncthreads();
    }
    int texcl = ssum[t] - tsum;
    lbase[4 * t]     = texcl;
    lbase[4 * t + 1] = texcl + cv.x;
    lbase[4 * t + 2] = texcl + cv.x + cv.y;
    lbase[4 * t + 3] = texcl + cv.x + cv.y + cv.z;
    lcur[4 * t]     = lbase[4 * t];
    lcur[4 * t + 1] = lbase[4 * t + 1];
    lcur[4 * t + 2] = lbase[4 * t + 2];
    lcur[4 * t + 3] = lbase[4 * t + 3];
    __syncthreads();

    // scan bucket totals -> base_s
    int4 bt = *(const int4*)&btot[4 * t];
    int bsum = bt.x + bt.y + bt.z + bt.w;
    ssum[t] = bsum;
    __syncthreads();
    for (int off = 1; off < 256; off <<= 1) {
        int x = (t >= off) ? ssum[t - off] : 0;
        __syncthreads();
        ssum[t] += x;
        __syncthreads();
    }
    int bexcl = ssum[t] - bsum;
    base_s[4 * t]     = bexcl;
    base_s[4 * t + 1] = bexcl + bt.x;
    base_s[4 * t + 2] = bexcl + bt.x + bt.y;
    base_s[4 * t + 3] = bexcl + bt.x + bt.y + bt.z;
    if (blk == 0) {
        *(int4*)&gbase[4 * t] = *(int4*)&base_s[4 * t];
        if (t == 255) gbase[NBUCK] = ssum[255];
    }
    __syncthreads();
    for (int i = t; i < NBUCK; i += 256)
        rb2[i] = base_s[i] + prefT[i * ncp + blk];
    __syncthreads();

    const int cb = blk * CHUNK, ce = min(cb + CHUNK, E);
    for (int e = cb + t; e < ce; e += 256) {
        int d = dst[e];
        int b = d >> BSH;
        unsigned packed = ((unsigned)src[e] << BSH) | (unsigned)(d & (BNODES - 1));
        int p = atomicAdd(&lcur[b], 1);
        sp[p] = packed;
        sb[p] = (ushort)b;
    }
    __syncthreads();
    const int cnt = ce - cb;
    for (int i = t; i < cnt; i += 256) {
        int b = sb[i];
        pairs[rb2[b] + (i - lbase[b])] = sp[i];
    }
}

// ---------------- K4: per-bucket CSR finalize ----------------
__global__ __launch_bounds__(256)
void bucket_csr(const unsigned* __restrict__ pairs, const int* __restrict__ base,
                int* __restrict__ row_start, float* __restrict__ dinv,
                unsigned* __restrict__ csr, int N, int E)
{
    __shared__ int deg[BNODES];
    __shared__ int s[BNODES];
    __shared__ int cur[BNODES];
    const int b = blockIdx.x, t = threadIdx.x;
    if (t < BNODES) deg[t] = 0;
    __syncthreads();
    const int rb = base[b], re = base[b + 1];
    for (int e = rb + t; e < re; e += 256)
        atomicAdd(&deg[pairs[e] & (BNODES - 1)], 1);
    __syncthreads();
    int v = (t < BNODES) ? deg[t] : 0;
    if (t < BNODES) s[t] = v;
    __syncthreads();
    for (int off = 1; off < BNODES; off <<= 1) {
        int x = (t >= off && t < BNODES) ? s[t - off] : 0;
        __syncthreads();
        if (t < BNODES) s[t] += x;
        __syncthreads();
    }
    const int n0 = b << BSH;
    if (t < BNODES) {
        int excl = s[t] - v;
        cur[t] = excl;
        if (n0 + t < N) {
            row_start[n0 + t] = rb + excl;
            dinv[n0 + t] = rsqrtf((float)v + 1.0f);
        }
    }
    if (b == gridDim.x - 1 && t == 0) row_start[N] = E;
    __syncthreads();
    for (int e = rb + t; e < re; e += 256) {
        unsigned p = pairs[e];
        int l = p & (BNODES - 1);
        int slot = atomicAdd(&cur[l], 1);
        csr[rb + slot] = p >> BSH;
    }
}

// ---------------- K5: fused pipelined GEMM: z' = (relu(x@W1^T+b1) @ W2^T) * dinv ----------------
// LDS map (ushorts): phase A dbuf As0@0 Bs0@5120 As1@10240 Bs1@15360 (40 KB);
// Ht@0 (34 KB, aliases phase-A bufs, barrier-protected); phase-B Bs@20480 (10 KB). Total 50 KB.
__global__ __launch_bounds__(256, 3)
void gemm_fused(const float* __restrict__ X, const ushort* __restrict__ W1b,
                const ushort* __restrict__ W2b, const float* __restrict__ b1,
                const float* __restrict__ dinv, ushort* __restrict__ Zq, int M)
{
    __shared__ ushort smem[25600];
    ushort* Ht  = smem;            // 128*LDH = 17408
    ushort* BsB = smem + 20480;    // 128*LDA = 5120
    const int tid = threadIdx.x;
    const int wave = tid >> 6, lane = tid & 63;
    const int wm = (wave & 1) * 64, wn = (wave >> 1) * 64;
    const int lr = lane & 15, lq = lane >> 4;
    const int m0 = blockIdx.x * 128;

    const int ldr  = tid >> 2;            // 0..63 staging row group base
    const int ldkq = (tid & 3) * 8;       // k-octet

    // ---- phase A: acc = x @ W1^T (K=256), reg-prefetch + LDS double-buffer ----
    f32x4 acc[4][4] = {};
    float4 ar[2][2];
    uint4  br[2];
    {
#pragma unroll
        for (int it = 0; it < 2; it++) {
            int row = ldr + it * 64;
            ar[it][0] = make_float4(0.f, 0.f, 0.f, 0.f);
            ar[it][1] = make_float4(0.f, 0.f, 0.f, 0.f);
            if (m0 + row < M) {
                ar[it][0] = *(const float4*)&X[(long)(m0 + row) * F_IN + ldkq];
                ar[it][1] = *(const float4*)&X[(long)(m0 + row) * F_IN + ldkq + 4];
            }
            br[it] = *(const uint4*)&W1b[(long)row * F_IN + ldkq];
        }
    }
    for (int k0 = 0; k0 < F_IN; k0 += 32) {
        ushort* As = smem + (k0 & 32) * 320;          // 0 or 10240
        ushort* Bs = As + 5120;
#pragma unroll
        for (int it = 0; it < 2; it++) {
            int row = ldr + it * 64;
            ushort u[8] = { f2bf(ar[it][0].x), f2bf(ar[it][0].y), f2bf(ar[it][0].z), f2bf(ar[it][0].w),
                            f2bf(ar[it][1].x), f2bf(ar[it][1].y), f2bf(ar[it][1].z), f2bf(ar[it][1].w) };
            *(uint4*)&As[row * LDA + ldkq] = *(uint4*)u;
            *(uint4*)&Bs[row * LDA + ldkq] = br[it];
        }
        __syncthreads();
        if (k0 + 32 < F_IN) {
            int kn = k0 + 32;
#pragma unroll
            for (int it = 0; it < 2; it++) {
                int row = ldr + it * 64;
                ar[it][0] = make_float4(0.f, 0.f, 0.f, 0.f);
                ar[it][1] = make_float4(0.f, 0.f, 0.f, 0.f);
                if (m0 + row < M) {
                    ar[it][0] = *(const float4*)&X[(long)(m0 + row) * F_IN + kn + ldkq];
                    ar[it][1] = *(const float4*)&X[(long)(m0 + row) * F_IN + kn + ldkq + 4];
                }
                br[it] = *(const uint4*)&W1b[(long)row * F_IN + kn + ldkq];
            }
        }
        bf16x8 af[4], bfr[4];
#pragma unroll
        for (int t4 = 0; t4 < 4; t4++) {
            af[t4]  = *(bf16x8*)&As[(wm + t4 * 16 + lr) * LDA + lq * 8];
            bfr[t4] = *(bf16x8*)&Bs[(wn + t4 * 16 + lr) * LDA + lq * 8];
        }
#pragma unroll
        for (int i = 0; i < 4; i++)
#pragma unroll
            for (int j = 0; j < 4; j++)
                acc[i][j] = __builtin_amdgcn_mfma_f32_16x16x32_bf16(af[i], bfr[j], acc[i][j], 0, 0, 0);
    }
    __syncthreads();   // all MFMA reads of phase-A buffers done before Ht overwrite

    // ---- epilogue A: h = relu(acc + b1) -> Ht ----
    {
        float bv[4];
#pragma unroll
        for (int j = 0; j < 4; j++) bv[j] = b1[wn + j * 16 + lr];
#pragma unroll
        for (int i = 0; i < 4; i++)
#pragma unroll
            for (int r = 0; r < 4; r++) {
                int row = wm + i * 16 + lq * 4 + r;
#pragma unroll
                for (int j = 0; j < 4; j++)
                    Ht[row * LDH + wn + j * 16 + lr] = f2bf(fmaxf(acc[i][j][r] + bv[j], 0.f));
            }
    }
    __syncthreads();

    // ---- phase B: acc2 = h @ W2^T (K=128), A from Ht, B single-buffered w/ reg prefetch ----
    f32x4 acc2[4][4] = {};
    {
#pragma unroll
        for (int it = 0; it < 2; it++)
            br[it] = *(const uint4*)&W2b[(long)(ldr + it * 64) * CCH + ldkq];
    }
    for (int k0 = 0; k0 < CCH; k0 += 32) {
#pragma unroll
        for (int it = 0; it < 2; it++)
            *(uint4*)&BsB[(ldr + it * 64) * LDA + ldkq] = br[it];
        __syncthreads();
        if (k0 + 32 < CCH) {
#pragma unroll
            for (int it = 0; it < 2; it++)
                br[it] = *(const uint4*)&W2b[(long)(ldr + it * 64) * CCH + k0 + 32 + ldkq];
        }
        bf16x8 af[4], bfr[4];
#pragma unroll
        for (int t4 = 0; t4 < 4; t4++) {
            af[t4]  = *(bf16x8*)&Ht[(wm + t4 * 16 + lr) * LDH + k0 + lq * 8];
            bfr[t4] = *(bf16x8*)&BsB[(wn + t4 * 16 + lr) * LDA + lq * 8];
        }
#pragma unroll
        for (int i = 0; i < 4; i++)
#pragma unroll
            for (int j = 0; j < 4; j++)
                acc2[i][j] = __builtin_amdgcn_mfma_f32_16x16x32_bf16(af[i], bfr[j], acc2[i][j], 0, 0, 0);
        __syncthreads();
    }

    // ---- epilogue B: z' = acc2 * dinv -> Ht -> coalesced store ----
#pragma unroll
    for (int i = 0; i < 4; i++)
#pragma unroll
        for (int r = 0; r < 4; r++) {
            int row = wm + i * 16 + lq * 4 + r;
            float di = (m0 + row < M) ? dinv[m0 + row] : 0.f;
#pragma unroll
            for (int j = 0; j < 4; j++)
                Ht[row * LDH + wn + j * 16 + lr] = f2bf(acc2[i][j][r] * di);
        }
    __syncthreads();
    {
        int colq = tid & 15, row0 = tid >> 4;
#pragma unroll
        for (int i = 0; i < 8; i++) {
            int row = row0 + i * 16;
            if (m0 + row < M)
                *(uint4*)&Zq[(long)(m0 + row) * CCH + colq * 8] =
                    *(uint4*)&Ht[row * LDH + colq * 8];
        }
    }
}

// ---------------- K6: gather ----------------
__global__ __launch_bounds__(256)
void gather_nodes(const unsigned* __restrict__ zq, const unsigned* __restrict__ csr,
                  const int* __restrict__ row_start, const float* __restrict__ dinv,
                  const float* __restrict__ b2, float* __restrict__ out, int N)
{
    const int node = blockIdx.x * 4 + (threadIdx.x >> 6);
    const int lane = threadIdx.x & 63;
    if (node >= N) return;

    float2 zs = bf2f2(zq[(long)node * 64 + lane]);
    float acc0 = zs.x, acc1 = zs.y;

    const int rs = row_start[node];
    const int re = row_start[node + 1];
    int j = rs;
    for (; j + 8 <= re; j += 8) {
        unsigned sI[8], zv[8];
#pragma unroll
        for (int q = 0; q < 8; q++) sI[q] = csr[j + q];
#pragma unroll
        for (int q = 0; q < 8; q++) zv[q] = zq[(long)sI[q] * 64 + lane];
#pragma unroll
        for (int q = 0; q < 8; q++) { float2 f = bf2f2(zv[q]); acc0 += f.x; acc1 += f.y; }
    }
    for (; j < re; j++) {
        float2 f = bf2f2(zq[(long)csr[j] * 64 + lane]);
        acc0 += f.x; acc1 += f.y;
    }

    float di = dinv[node];
    float2 o;
    o.x = b2[lane * 2 + 0] + di * acc0;
    o.y = b2[lane * 2 + 1] + di * acc1;
    *(float2*)&out[(long)node * CCH + lane * 2] = o;
}

extern "C" void kernel_launch(void* const* d_in, const int* in_sizes, int n_in,
                              void* d_out, int out_size, void* d_ws, size_t ws_size,
                              hipStream_t stream)
{
    const float* x  = (const float*)d_in[0];
    const int*   ei = (const int*)d_in[1];
    const float* W1 = (const float*)d_in[2];
    const float* b1 = (const float*)d_in[3];
    const float* W2 = (const float*)d_in[4];
    const float* b2 = (const float*)d_in[5];
    float* out = (float*)d_out;

    const int N = in_sizes[0] / F_IN;
    const int E = in_sizes[1] / 2;
    const int* src = ei;
    const int* dst = ei + E;

    const int nchunks = (E + CHUNK - 1) / CHUNK;        // 782
    const int ncp     = (nchunks + 63) & ~63;           // 832
    const int nbuck   = (N + BNODES - 1) / BNODES;      // 782
    const int ngrid   = (N + 127) / 128;
    const int ncvt    = (CCH * F_IN + CCH * CCH + 255) / 256;

    char* ws = (char*)d_ws;
    ushort* zq    = (ushort*)ws;   ws += (size_t)N * CCH * 2;
    ushort* w1b   = (ushort*)ws;   ws += (size_t)CCH * F_IN * 2;
    ushort* w2b   = (ushort*)ws;   ws += (size_t)CCH * CCH * 2;
    unsigned* prs = (unsigned*)ws; ws += (size_t)E * 4;
    unsigned* csr = (unsigned*)ws; ws += (size_t)E * 4;
    int* rstart   = (int*)ws;      ws += ((size_t)N + 1) * 4;
    float* dinv   = (float*)ws;    ws += (size_t)N * 4;
    int* histC    = (int*)ws;      ws += (size_t)nchunks * NBUCK * 4;
    int* histT    = (int*)ws;      ws += (size_t)NBUCK * ncp * 4;
    int* prefT    = (int*)ws;      ws += (size_t)NBUCK * ncp * 4;
    int* btot     = (int*)ws;      ws += NBUCK * 4;
    int* gbase    = (int*)ws;      ws += (NBUCK + 1) * 4;

    // build
    hist_cvt<<<nchunks + ncvt, 256, 0, stream>>>(dst, histC, histT, E, nchunks, ncp, W1, W2, w1b, w2b);
    scan_buckets<<<NBUCK / 4, 256, 0, stream>>>(histT, prefT, btot, nchunks, ncp);
    partition_kernel<<<nchunks, 256, 0, stream>>>(src, dst, histC, prefT, btot, gbase, prs, E, ncp);
    bucket_csr<<<nbuck, 256, 0, stream>>>(prs, gbase, rstart, dinv, csr, N, E);

    // fused GEMMs: z' = (relu(x@W1^T + b1) @ W2^T) * dinv   [bf16]
    gemm_fused<<<ngrid, 256, 0, stream>>>(x, w1b, w2b, b1, dinv, zq, N);

    // aggregate
    gather_nodes<<<(N + 3) / 4, 256, 0, stream>>>((const unsigned*)zq, csr, rstart, dinv, b2, out, N);
}

// Round 8
// 329.397 us; speedup vs baseline: 1.0381x; 1.0381x over previous
//
#include <hip/hip_runtime.h>

typedef unsigned short ushort;
typedef __bf16 bf16x8 __attribute__((ext_vector_type(8)));
typedef float f32x4 __attribute__((ext_vector_type(4)));

#define F_IN 256
#define CCH  128
#define BSH  7
#define BNODES 128
#define NBUCK 1024
#define CHUNK 2048

#define LDA 40    // ushort stride of staged A/B rows (BK=32 + 8 pad)
#define LDH 136   // ushort stride of h-tile rows

// ---------------- helpers ----------------
__device__ __forceinline__ ushort f2bf(float f) {
    union { float f; unsigned i; } u; u.f = f;
    unsigned r = u.i + 0x7fffu + ((u.i >> 16) & 1u);   // RNE
    return (ushort)(r >> 16);
}
__device__ __forceinline__ float2 bf2f2(unsigned u) {
    union { unsigned i; float f; } lo, hi;
    lo.i = u << 16;
    hi.i = u & 0xffff0000u;
    return make_float2(lo.f, hi.f);
}

// ---------------- K1: per-chunk histogram (dual layout) + weight cvt ----------------
__global__ __launch_bounds__(256)
void hist_cvt(const int* __restrict__ dst, int* __restrict__ histC, int* __restrict__ histT,
              int E, int nchunks, int ncp,
              const float* __restrict__ W1, const float* __restrict__ W2,
              ushort* __restrict__ w1b, ushort* __restrict__ w2b)
{
    const int blk = blockIdx.x, t = threadIdx.x;
    if (blk >= nchunks) {
        int i = (blk - nchunks) * 256 + t;
        if (i < CCH * F_IN) w1b[i] = f2bf(W1[i]);
        else {
            int j = i - CCH * F_IN;
            if (j < CCH * CCH) w2b[j] = f2bf(W2[j]);
        }
        return;
    }
    __shared__ int h[NBUCK];
    for (int i = t; i < NBUCK; i += 256) h[i] = 0;
    __syncthreads();
    int cb = blk * CHUNK, ce = min(cb + CHUNK, E);
    for (int e = cb + t; e < ce; e += 256)
        atomicAdd(&h[dst[e] >> BSH], 1);
    __syncthreads();
    for (int i = t; i < NBUCK; i += 256) {
        int v = h[i];
        histC[blk * NBUCK + i] = v;     // chunk-major (partition)
        histT[i * ncp + blk]   = v;     // bucket-major (scan)
    }
}

// ---------------- K2: per-bucket cross-chunk prefix (one wave per bucket) ----------------
__global__ __launch_bounds__(256)
void scan_buckets(const int* __restrict__ histT, int* __restrict__ prefT,
                  int* __restrict__ btot, int nchunks, int ncp)
{
    const int b = blockIdx.x * 4 + (threadIdx.x >> 6);
    const int lane = threadIdx.x & 63;
    int carry = 0;
    for (int c = 0; c < nchunks; c += 64) {
        int idx = c + lane;
        int v = (idx < nchunks) ? histT[b * ncp + idx] : 0;
        int inc = v;
#pragma unroll
        for (int off = 1; off < 64; off <<= 1) {
            int x = __shfl_up(inc, off, 64);
            if (lane >= off) inc += x;
        }
        if (idx < nchunks) prefT[b * ncp + idx] = carry + inc - v;
        carry += __shfl(inc, 63, 64);
    }
    if (lane == 0) btot[b] = carry;
}

// ---------------- K3: partition (deterministic slots, no global atomics) ----------------
__global__ __launch_bounds__(256)
void partition_kernel(const int* __restrict__ src, const int* __restrict__ dst,
                      const int* __restrict__ histC, const int* __restrict__ prefT,
                      const int* __restrict__ btot, int* __restrict__ gbase,
                      unsigned* __restrict__ pairs, int E, int ncp)
{
    __shared__ int lbase[NBUCK];
    __shared__ int lcur[NBUCK];
    __shared__ int rb2[NBUCK];
    __shared__ int base_s[NBUCK];
    __shared__ int ssum[256];
    __shared__ unsigned sp[CHUNK];   // 8 KB
    __shared__ ushort  sb[CHUNK];    // 4 KB
    const int t = threadIdx.x, blk = blockIdx.x;

    // scan this chunk's hist -> lbase/lcur
    int4 cv = *(const int4*)&histC[blk * NBUCK + 4 * t];
    int tsum = cv.x + cv.y + cv.z + cv.w;
    ssum[t] = tsum;
    __syncthreads();
    for (int off = 1; off < 256; off <<= 1) {
        int x = (t >= off) ? ssum[t - off] : 0;
        __syncthreads();
        ssum[t] += x;
        __syncthreads();
    }
    int texcl = ssum[t] - tsum;
    lbase[4 * t]     = texcl;
    lbase[4 * t + 1] = texcl + cv.x;
    lbase[4 * t + 2] = texcl + cv.x + cv.y;
    lbase[4 * t + 3] = texcl + cv.x + cv.y + cv.z;
    lcur[4 * t]     = lbase[4 * t];
    lcur[4 * t + 1] = lbase[4 * t + 1];
    lcur[4 * t + 2] = lbase[4 * t + 2];
    lcur[4 * t + 3] = lbase[4 * t + 3];
    __syncthreads();

    // scan bucket totals -> base_s
    int4 bt = *(const int4*)&btot[4 * t];
    int bsum = bt.x + bt.y + bt.z + bt.w;
    ssum[t] = bsum;
    __syncthreads();
    for (int off = 1; off < 256; off <<= 1) {
        int x = (t >= off) ? ssum[t - off] : 0;
        __syncthreads();
        ssum[t] += x;
        __syncthreads();
    }
    int bexcl = ssum[t] - bsum;
    base_s[4 * t]     = bexcl;
    base_s[4 * t + 1] = bexcl + bt.x;
    base_s[4 * t + 2] = bexcl + bt.x + bt.y;
    base_s[4 * t + 3] = bexcl + bt.x + bt.y + bt.z;
    if (blk == 0) {
        *(int4*)&gbase[4 * t] = *(int4*)&base_s[4 * t];
        if (t == 255) gbase[NBUCK] = ssum[255];
    }
    __syncthreads();
    for (int i = t; i < NBUCK; i += 256)
        rb2[i] = base_s[i] + prefT[i * ncp + blk];
    __syncthreads();

    const int cb = blk * CHUNK, ce = min(cb + CHUNK, E);
    for (int e = cb + t; e < ce; e += 256) {
        int d = dst[e];
        int b = d >> BSH;
        unsigned packed = ((unsigned)src[e] << BSH) | (unsigned)(d & (BNODES - 1));
        int p = atomicAdd(&lcur[b], 1);
        sp[p] = packed;
        sb[p] = (ushort)b;
    }
    __syncthreads();
    const int cnt = ce - cb;
    for (int i = t; i < cnt; i += 256) {
        int b = sb[i];
        pairs[rb2[b] + (i - lbase[b])] = sp[i];
    }
}

// ---------------- K4: per-bucket CSR finalize ----------------
__global__ __launch_bounds__(256)
void bucket_csr(const unsigned* __restrict__ pairs, const int* __restrict__ base,
                int* __restrict__ row_start, float* __restrict__ dinv,
                unsigned* __restrict__ csr, int N, int E)
{
    __shared__ int deg[BNODES];
    __shared__ int s[BNODES];
    __shared__ int cur[BNODES];
    const int b = blockIdx.x, t = threadIdx.x;
    if (t < BNODES) deg[t] = 0;
    __syncthreads();
    const int rb = base[b], re = base[b + 1];
    for (int e = rb + t; e < re; e += 256)
        atomicAdd(&deg[pairs[e] & (BNODES - 1)], 1);
    __syncthreads();
    int v = (t < BNODES) ? deg[t] : 0;
    if (t < BNODES) s[t] = v;
    __syncthreads();
    for (int off = 1; off < BNODES; off <<= 1) {
        int x = (t >= off && t < BNODES) ? s[t - off] : 0;
        __syncthreads();
        if (t < BNODES) s[t] += x;
        __syncthreads();
    }
    const int n0 = b << BSH;
    if (t < BNODES) {
        int excl = s[t] - v;
        cur[t] = excl;
        if (n0 + t < N) {
            row_start[n0 + t] = rb + excl;
            dinv[n0 + t] = rsqrtf((float)v + 1.0f);
        }
    }
    if (b == gridDim.x - 1 && t == 0) row_start[N] = E;
    __syncthreads();
    for (int e = rb + t; e < re; e += 256) {
        unsigned p = pairs[e];
        int l = p & (BNODES - 1);
        int slot = atomicAdd(&cur[l], 1);
        csr[rb + slot] = p >> BSH;
    }
}

// ---------------- K5: fused pipelined GEMM: z' = (relu(x@W1^T+b1) @ W2^T) * dinv ----------------
// LDS (ushort idx): phase-A dbuf As0@0 Bs0@5120 As1@10240 Bs1@15360 (dead after phase A);
// Ht@0 (17408 ush, aliases dbuf); phase-B Bs@17408 (5120 ush, aliases dbuf tail).
// Total 22528 ush = 45056 B -> 3 blocks/CU. No waves cap: let allocator use VGPRs (R6's
// __launch_bounds__(256,3) caused ~35 MB scratch-spill traffic, WRITE_SIZE 61 MB).
__global__ __launch_bounds__(256)
void gemm_fused(const float* __restrict__ X, const ushort* __restrict__ W1b,
                const ushort* __restrict__ W2b, const float* __restrict__ b1,
                const float* __restrict__ dinv, ushort* __restrict__ Zq, int M)
{
    __shared__ ushort smem[22528];
    ushort* Ht  = smem;            // 128*LDH = 17408
    ushort* BsB = smem + 17408;    // 128*LDA = 5120
    const int tid = threadIdx.x;
    const int wave = tid >> 6, lane = tid & 63;
    const int wm = (wave & 1) * 64, wn = (wave >> 1) * 64;
    const int lr = lane & 15, lq = lane >> 4;
    const int m0 = blockIdx.x * 128;

    const int ldr  = tid >> 2;            // 0..63 staging row group base
    const int ldkq = (tid & 3) * 8;       // k-octet

    // ---- phase A: acc = x @ W1^T (K=256), reg-prefetch + LDS double-buffer ----
    f32x4 acc[4][4] = {};
    float4 ar[2][2];
    uint4  br[2];
    {
#pragma unroll
        for (int it = 0; it < 2; it++) {
            int row = ldr + it * 64;
            ar[it][0] = make_float4(0.f, 0.f, 0.f, 0.f);
            ar[it][1] = make_float4(0.f, 0.f, 0.f, 0.f);
            if (m0 + row < M) {
                ar[it][0] = *(const float4*)&X[(long)(m0 + row) * F_IN + ldkq];
                ar[it][1] = *(const float4*)&X[(long)(m0 + row) * F_IN + ldkq + 4];
            }
            br[it] = *(const uint4*)&W1b[(long)row * F_IN + ldkq];
        }
    }
    for (int k0 = 0; k0 < F_IN; k0 += 32) {
        ushort* As = smem + (k0 & 32) * 320;          // 0 or 10240 (ushort idx)
        ushort* Bs = As + 5120;
#pragma unroll
        for (int it = 0; it < 2; it++) {
            int row = ldr + it * 64;
            ushort u[8] = { f2bf(ar[it][0].x), f2bf(ar[it][0].y), f2bf(ar[it][0].z), f2bf(ar[it][0].w),
                            f2bf(ar[it][1].x), f2bf(ar[it][1].y), f2bf(ar[it][1].z), f2bf(ar[it][1].w) };
            *(uint4*)&As[row * LDA + ldkq] = *(uint4*)u;
            *(uint4*)&Bs[row * LDA + ldkq] = br[it];
        }
        __syncthreads();
        if (k0 + 32 < F_IN) {
            int kn = k0 + 32;
#pragma unroll
            for (int it = 0; it < 2; it++) {
                int row = ldr + it * 64;
                ar[it][0] = make_float4(0.f, 0.f, 0.f, 0.f);
                ar[it][1] = make_float4(0.f, 0.f, 0.f, 0.f);
                if (m0 + row < M) {
                    ar[it][0] = *(const float4*)&X[(long)(m0 + row) * F_IN + kn + ldkq];
                    ar[it][1] = *(const float4*)&X[(long)(m0 + row) * F_IN + kn + ldkq + 4];
                }
                br[it] = *(const uint4*)&W1b[(long)row * F_IN + kn + ldkq];
            }
        }
        bf16x8 af[4], bfr[4];
#pragma unroll
        for (int t4 = 0; t4 < 4; t4++) {
            af[t4]  = *(bf16x8*)&As[(wm + t4 * 16 + lr) * LDA + lq * 8];
            bfr[t4] = *(bf16x8*)&Bs[(wn + t4 * 16 + lr) * LDA + lq * 8];
        }
#pragma unroll
        for (int i = 0; i < 4; i++)
#pragma unroll
            for (int j = 0; j < 4; j++)
                acc[i][j] = __builtin_amdgcn_mfma_f32_16x16x32_bf16(af[i], bfr[j], acc[i][j], 0, 0, 0);
    }
    __syncthreads();   // all MFMA reads of dbuf done before Ht overwrite

    // ---- epilogue A: h = relu(acc + b1) -> Ht ----
    {
        float bv[4];
#pragma unroll
        for (int j = 0; j < 4; j++) bv[j] = b1[wn + j * 16 + lr];
#pragma unroll
        for (int i = 0; i < 4; i++)
#pragma unroll
            for (int r = 0; r < 4; r++) {
                int row = wm + i * 16 + lq * 4 + r;
#pragma unroll
                for (int j = 0; j < 4; j++)
                    Ht[row * LDH + wn + j * 16 + lr] = f2bf(fmaxf(acc[i][j][r] + bv[j], 0.f));
            }
    }
    __syncthreads();

    // ---- phase B: acc2 = h @ W2^T (K=128), A from Ht, B single-buffered w/ reg prefetch ----
    f32x4 acc2[4][4] = {};
    {
#pragma unroll
        for (int it = 0; it < 2; it++)
            br[it] = *(const uint4*)&W2b[(long)(ldr + it * 64) * CCH + ldkq];
    }
    for (int k0 = 0; k0 < CCH; k0 += 32) {
#pragma unroll
        for (int it = 0; it < 2; it++)
            *(uint4*)&BsB[(ldr + it * 64) * LDA + ldkq] = br[it];
        __syncthreads();
        if (k0 + 32 < CCH) {
#pragma unroll
            for (int it = 0; it < 2; it++)
                br[it] = *(const uint4*)&W2b[(long)(ldr + it * 64) * CCH + k0 + 32 + ldkq];
        }
        bf16x8 af[4], bfr[4];
#pragma unroll
        for (int t4 = 0; t4 < 4; t4++) {
            af[t4]  = *(bf16x8*)&Ht[(wm + t4 * 16 + lr) * LDH + k0 + lq * 8];
            bfr[t4] = *(bf16x8*)&BsB[(wn + t4 * 16 + lr) * LDA + lq * 8];
        }
#pragma unroll
        for (int i = 0; i < 4; i++)
#pragma unroll
            for (int j = 0; j < 4; j++)
                acc2[i][j] = __builtin_amdgcn_mfma_f32_16x16x32_bf16(af[i], bfr[j], acc2[i][j], 0, 0, 0);
        __syncthreads();
    }

    // ---- epilogue B: z' = acc2 * dinv -> Ht -> coalesced store ----
#pragma unroll
    for (int i = 0; i < 4; i++)
#pragma unroll
        for (int r = 0; r < 4; r++) {
            int row = wm + i * 16 + lq * 4 + r;
            float di = (m0 + row < M) ? dinv[m0 + row] : 0.f;
#pragma unroll
            for (int j = 0; j < 4; j++)
                Ht[row * LDH + wn + j * 16 + lr] = f2bf(acc2[i][j][r] * di);
        }
    __syncthreads();
    {
        int colq = tid & 15, row0 = tid >> 4;
#pragma unroll
        for (int i = 0; i < 8; i++) {
            int row = row0 + i * 16;
            if (m0 + row < M)
                *(uint4*)&Zq[(long)(m0 + row) * CCH + colq * 8] =
                    *(uint4*)&Ht[row * LDH + colq * 8];
        }
    }
}

// ---------------- K6: gather ----------------
__global__ __launch_bounds__(256)
void gather_nodes(const unsigned* __restrict__ zq, const unsigned* __restrict__ csr,
                  const int* __restrict__ row_start, const float* __restrict__ dinv,
                  const float* __restrict__ b2, float* __restrict__ out, int N)
{
    const int node = blockIdx.x * 4 + (threadIdx.x >> 6);
    const int lane = threadIdx.x & 63;
    if (node >= N) return;

    float2 zs = bf2f2(zq[(long)node * 64 + lane]);
    float acc0 = zs.x, acc1 = zs.y;

    const int rs = row_start[node];
    const int re = row_start[node + 1];
    int j = rs;
    for (; j + 8 <= re; j += 8) {
        unsigned sI[8], zv[8];
#pragma unroll
        for (int q = 0; q < 8; q++) sI[q] = csr[j + q];
#pragma unroll
        for (int q = 0; q < 8; q++) zv[q] = zq[(long)sI[q] * 64 + lane];
#pragma unroll
        for (int q = 0; q < 8; q++) { float2 f = bf2f2(zv[q]); acc0 += f.x; acc1 += f.y; }
    }
    for (; j < re; j++) {
        float2 f = bf2f2(zq[(long)csr[j] * 64 + lane]);
        acc0 += f.x; acc1 += f.y;
    }

    float di = dinv[node];
    float2 o;
    o.x = b2[lane * 2 + 0] + di * acc0;
    o.y = b2[lane * 2 + 1] + di * acc1;
    *(float2*)&out[(long)node * CCH + lane * 2] = o;
}

extern "C" void kernel_launch(void* const* d_in, const int* in_sizes, int n_in,
                              void* d_out, int out_size, void* d_ws, size_t ws_size,
                              hipStream_t stream)
{
    const float* x  = (const float*)d_in[0];
    const int*   ei = (const int*)d_in[1];
    const float* W1 = (const float*)d_in[2];
    const float* b1 = (const float*)d_in[3];
    const float* W2 = (const float*)d_in[4];
    const float* b2 = (const float*)d_in[5];
    float* out = (float*)d_out;

    const int N = in_sizes[0] / F_IN;
    const int E = in_sizes[1] / 2;
    const int* src = ei;
    const int* dst = ei + E;

    const int nchunks = (E + CHUNK - 1) / CHUNK;        // 782
    const int ncp     = (nchunks + 63) & ~63;           // 832
    const int nbuck   = (N + BNODES - 1) / BNODES;      // 782
    const int ngrid   = (N + 127) / 128;
    const int ncvt    = (CCH * F_IN + CCH * CCH + 255) / 256;

    char* ws = (char*)d_ws;
    ushort* zq    = (ushort*)ws;   ws += (size_t)N * CCH * 2;
    ushort* w1b   = (ushort*)ws;   ws += (size_t)CCH * F_IN * 2;
    ushort* w2b   = (ushort*)ws;   ws += (size_t)CCH * CCH * 2;
    unsigned* prs = (unsigned*)ws; ws += (size_t)E * 4;
    unsigned* csr = (unsigned*)ws; ws += (size_t)E * 4;
    int* rstart   = (int*)ws;      ws += ((size_t)N + 1) * 4;
    float* dinv   = (float*)ws;    ws += (size_t)N * 4;
    int* histC    = (int*)ws;      ws += (size_t)nchunks * NBUCK * 4;
    int* histT    = (int*)ws;      ws += (size_t)NBUCK * ncp * 4;
    int* prefT    = (int*)ws;      ws += (size_t)NBUCK * ncp * 4;
    int* btot     = (int*)ws;      ws += NBUCK * 4;
    int* gbase    = (int*)ws;      ws += (NBUCK + 1) * 4;

    // build
    hist_cvt<<<nchunks + ncvt, 256, 0, stream>>>(dst, histC, histT, E, nchunks, ncp, W1, W2, w1b, w2b);
    scan_buckets<<<NBUCK / 4, 256, 0, stream>>>(histT, prefT, btot, nchunks, ncp);
    partition_kernel<<<nchunks, 256, 0, stream>>>(src, dst, histC, prefT, btot, gbase, prs, E, ncp);
    bucket_csr<<<nbuck, 256, 0, stream>>>(prs, gbase, rstart, dinv, csr, N, E);

    // fused GEMMs: z' = (relu(x@W1^T + b1) @ W2^T) * dinv   [bf16]
    gemm_fused<<<ngrid, 256, 0, stream>>>(x, w1b, w2b, b1, dinv, zq, N);

    // aggregate
    gather_nodes<<<(N + 3) / 4, 256, 0, stream>>>((const unsigned*)zq, csr, rstart, dinv, b2, out, N);
}